// Round 1
// baseline (618.822 us; speedup 1.0000x reference)
//
#include <hip/hip_runtime.h>

// GCN 2-layer: x[N,128] -> GCNConv(W1[128,64], b1) -> ReLU -> GCNConv(W2[64,32], b2)
// Strategy: factor norm = dinv[src]*dinv[dst]; pre-scale h by dinv, aggregate, post-scale.
// Build CSR (by dst) once per call, reuse for both layers. Gather-style aggregation
// (register accumulate, one coalesced store) instead of atomic scatter.

#define BLK 256

// --- edge-index dtype detection: if stored as int64 little-endian, every odd
// 32-bit word of the first values is the (zero) high half.
__global__ void k_detect(const int* __restrict__ idx, int* __restrict__ flag) {
    if (threadIdx.x == 0 && blockIdx.x == 0) {
        int z = 0;
#pragma unroll
        for (int i = 1; i < 32; i += 2) z |= idx[i];
        flag[0] = (z == 0) ? 1 : 0;
    }
}

__device__ __forceinline__ int edge_src(const int* idx, int e, int E, int is64) {
    return is64 ? idx[2 * e] : idx[e];
}
__device__ __forceinline__ int edge_dst(const int* idx, int e, int E, int is64) {
    return is64 ? idx[2 * (E + e)] : idx[E + e];
}

__global__ void k_count(const int* __restrict__ idx, int* __restrict__ counts,
                        const int* __restrict__ flag, int E) {
    int e = blockIdx.x * blockDim.x + threadIdx.x;
    if (e >= E) return;
    int is64 = flag[0];
    atomicAdd(&counts[edge_dst(idx, e, E, is64)], 1);
}

__global__ void k_dinv(const int* __restrict__ counts, float* __restrict__ dinv, int N) {
    int i = blockIdx.x * blockDim.x + threadIdx.x;
    if (i < N) dinv[i] = rsqrtf((float)(counts[i] + 1));  // +1 self-loop; always > 0
}

// ---- 3-phase exclusive scan of counts[N] -> row_ptr[N+1] (nb <= 512 blocks of 256)
__global__ void k_scan1(const int* __restrict__ counts, int* __restrict__ bsums, int N) {
    __shared__ int s[256];
    int i = blockIdx.x * 256 + threadIdx.x;
    s[threadIdx.x] = (i < N) ? counts[i] : 0;
    __syncthreads();
    for (int st = 128; st > 0; st >>= 1) {
        if (threadIdx.x < st) s[threadIdx.x] += s[threadIdx.x + st];
        __syncthreads();
    }
    if (threadIdx.x == 0) bsums[blockIdx.x] = s[0];
}

__global__ void k_scan2(const int* __restrict__ bsums, int* __restrict__ boffs, int nb) {
    __shared__ int s[512];
    int t = threadIdx.x;
    s[t] = (t < nb) ? bsums[t] : 0;
    __syncthreads();
    for (int st = 1; st < 512; st <<= 1) {
        int v = (t >= st) ? s[t - st] : 0;
        __syncthreads();
        s[t] += v;
        __syncthreads();
    }
    boffs[t] = (t == 0) ? 0 : s[t - 1];  // exclusive
}

__global__ void k_scan3(const int* __restrict__ counts, const int* __restrict__ boffs,
                        int* __restrict__ row_ptr, int N, int E) {
    __shared__ int s[256];
    int i = blockIdx.x * 256 + threadIdx.x;
    int v = (i < N) ? counts[i] : 0;
    s[threadIdx.x] = v;
    __syncthreads();
    for (int st = 1; st < 256; st <<= 1) {
        int u = (threadIdx.x >= st) ? s[threadIdx.x - st] : 0;
        __syncthreads();
        s[threadIdx.x] += u;
        __syncthreads();
    }
    if (i < N) row_ptr[i] = boffs[blockIdx.x] + s[threadIdx.x] - v;  // exclusive
    if (i == 0) row_ptr[N] = E;
}

__global__ void k_fill(const int* __restrict__ idx, const int* __restrict__ row_ptr,
                       int* __restrict__ cursor, int* __restrict__ csr_src,
                       const int* __restrict__ flag, int E) {
    int e = blockIdx.x * blockDim.x + threadIdx.x;
    if (e >= E) return;
    int is64 = flag[0];
    int s_ = edge_src(idx, e, E, is64);
    int d_ = edge_dst(idx, e, E, is64);
    int pos = atomicAdd(&cursor[d_], 1);
    csr_src[row_ptr[d_] + pos] = s_;
}

// ---- layer 1 GEMM: hs1[i,f] = (sum_k x[i,k] * W1[k,f]) * dinv[i], f in [0,64)
__global__ void k_gemm1(const float* __restrict__ x, const float* __restrict__ W1,
                        const float* __restrict__ dinv, float* __restrict__ hs1, int N) {
    __shared__ float xs[4][128];
    int sub = threadIdx.x >> 6;
    int f = threadIdx.x & 63;
    int r = blockIdx.x * 4 + sub;
    int rl = (r < N) ? r : (N - 1);
    xs[sub][f] = x[(size_t)rl * 128 + f];
    xs[sub][f + 64] = x[(size_t)rl * 128 + f + 64];
    __syncthreads();
    float acc = 0.f;
#pragma unroll
    for (int k = 0; k < 128; ++k)
        acc = fmaf(xs[sub][k], W1[k * 64 + f], acc);
    if (r < N) hs1[(size_t)r * 64 + f] = acc * dinv[r];
}

// ---- layer 1 aggregation: one wave (64 lanes) per node; register accumulate
__global__ void k_agg1(const float* __restrict__ hs1, const int* __restrict__ row_ptr,
                       const int* __restrict__ csr_src, const float* __restrict__ dinv,
                       const float* __restrict__ b1, float* __restrict__ a1, int N) {
    int node = blockIdx.x * 4 + (threadIdx.x >> 6);
    int f = threadIdx.x & 63;
    if (node >= N) return;
    float acc = hs1[(size_t)node * 64 + f];  // self-loop (already dinv-scaled)
    int beg = row_ptr[node], end = row_ptr[node + 1];
    for (int e = beg; e < end; ++e) {
        int j = csr_src[e];
        acc += hs1[(size_t)j * 64 + f];
    }
    float v = acc * dinv[node] + b1[f];
    a1[(size_t)node * 64 + f] = fmaxf(v, 0.f);
}

// ---- layer 2 GEMM: hs2[i,f] = (sum_k a1[i,k] * W2[k,f]) * dinv[i], f in [0,32)
__global__ void k_gemm2(const float* __restrict__ a1, const float* __restrict__ W2,
                        const float* __restrict__ dinv, float* __restrict__ hs2, int N) {
    __shared__ float as[8][64];
    int sub = threadIdx.x >> 5;
    int f = threadIdx.x & 31;
    int r = blockIdx.x * 8 + sub;
    int rl = (r < N) ? r : (N - 1);
    as[sub][f] = a1[(size_t)rl * 64 + f];
    as[sub][f + 32] = a1[(size_t)rl * 64 + f + 32];
    __syncthreads();
    float acc = 0.f;
#pragma unroll
    for (int k = 0; k < 64; ++k)
        acc = fmaf(as[sub][k], W2[k * 32 + f], acc);
    if (r < N) hs2[(size_t)r * 32 + f] = acc * dinv[r];
}

// ---- layer 2 aggregation: half-wave (32 lanes) per node
__global__ void k_agg2(const float* __restrict__ hs2, const int* __restrict__ row_ptr,
                       const int* __restrict__ csr_src, const float* __restrict__ dinv,
                       const float* __restrict__ b2, float* __restrict__ out, int N) {
    int node = blockIdx.x * 8 + (threadIdx.x >> 5);
    int f = threadIdx.x & 31;
    if (node >= N) return;
    float acc = hs2[(size_t)node * 32 + f];  // self-loop
    int beg = row_ptr[node], end = row_ptr[node + 1];
    for (int e = beg; e < end; ++e) {
        int j = csr_src[e];
        acc += hs2[(size_t)j * 32 + f];
    }
    out[(size_t)node * 32 + f] = acc * dinv[node] + b2[f];
}

extern "C" void kernel_launch(void* const* d_in, const int* in_sizes, int n_in,
                              void* d_out, int out_size, void* d_ws, size_t ws_size,
                              hipStream_t stream) {
    const float* x  = (const float*)d_in[0];
    const int*   idx = (const int*)d_in[1];
    const float* W1 = (const float*)d_in[2];
    const float* b1 = (const float*)d_in[3];
    const float* W2 = (const float*)d_in[4];
    const float* b2 = (const float*)d_in[5];
    float* out = (float*)d_out;

    const int N = in_sizes[0] / 128;   // 100000
    const int E = in_sizes[1] / 2;     // 1600000

    // workspace layout (256B aligned)
    char* ws = (char*)d_ws;
    size_t off = 0;
    auto alloc = [&](size_t bytes) -> char* {
        char* p = ws + off;
        off = (off + bytes + 255) & ~(size_t)255;
        return p;
    };
    int*   flag    = (int*)alloc(4);
    float* dinv    = (float*)alloc((size_t)N * 4);
    int*   counts  = (int*)alloc((size_t)N * 4);
    int*   row_ptr = (int*)alloc((size_t)(N + 1) * 4);
    int*   bsums   = (int*)alloc(512 * 4);
    int*   boffs   = (int*)alloc(512 * 4);
    int*   csr_src = (int*)alloc((size_t)E * 4);
    float* hs1     = (float*)alloc((size_t)N * 64 * 4);
    float* a1      = (float*)alloc((size_t)N * 64 * 4);
    float* hs2     = hs1;  // reuse: hs1 dead after k_agg1

    const int nb  = (N + 255) / 256;           // scan blocks (391 <= 512)
    const int ebk = (E + BLK - 1) / BLK;

    hipMemsetAsync(counts, 0, (size_t)N * 4, stream);
    k_detect<<<1, 1, 0, stream>>>(idx, flag);
    k_count<<<ebk, BLK, 0, stream>>>(idx, counts, flag, E);
    k_dinv<<<(N + BLK - 1) / BLK, BLK, 0, stream>>>(counts, dinv, N);
    k_scan1<<<nb, 256, 0, stream>>>(counts, bsums, N);
    k_scan2<<<1, 512, 0, stream>>>(bsums, boffs, nb);
    k_scan3<<<nb, 256, 0, stream>>>(counts, boffs, row_ptr, N, E);
    hipMemsetAsync(counts, 0, (size_t)N * 4, stream);  // reuse as fill cursor
    k_fill<<<ebk, BLK, 0, stream>>>(idx, row_ptr, counts, csr_src, flag, E);

    k_gemm1<<<(N + 3) / 4, 256, 0, stream>>>(x, W1, dinv, hs1, N);
    k_agg1<<<(N + 3) / 4, 256, 0, stream>>>(hs1, row_ptr, csr_src, dinv, b1, a1, N);
    k_gemm2<<<(N + 7) / 8, 256, 0, stream>>>(a1, W2, dinv, hs2, N);
    k_agg2<<<(N + 7) / 8, 256, 0, stream>>>(hs2, row_ptr, csr_src, dinv, b2, out, N);
}

// Round 2
// 428.780 us; speedup vs baseline: 1.4432x; 1.4432x over previous
//
#include <hip/hip_runtime.h>

// GCN 2-layer: x[N,128] -> GCNConv(W1[128,64], b1) -> ReLU -> GCNConv(W2[64,32], b2)
// norm = dinv[src]*dinv[dst] factorized: pre-scale h by dinv, aggregate, post-scale.
// CSR (by dst) built once per call, reused by both layers.
// Aggregation: one wave per node, lanes split into groups so 8-16 independent
// row gathers are in flight per wave (round-1 version was ~1 -> latency-bound).

#define BLK 256

__device__ __forceinline__ float4 shfl_xor4(float4 v, int m) {
    v.x = __shfl_xor(v.x, m, 64);
    v.y = __shfl_xor(v.y, m, 64);
    v.z = __shfl_xor(v.z, m, 64);
    v.w = __shfl_xor(v.w, m, 64);
    return v;
}
__device__ __forceinline__ void add4(float4& a, const float4 b) {
    a.x += b.x; a.y += b.y; a.z += b.z; a.w += b.w;
}

// --- edge-index dtype detection: if stored as int64 little-endian, every odd
// 32-bit word of the first values is the (zero) high half.
__global__ void k_detect(const int* __restrict__ idx, int* __restrict__ flag) {
    if (threadIdx.x == 0 && blockIdx.x == 0) {
        int z = 0;
#pragma unroll
        for (int i = 1; i < 32; i += 2) z |= idx[i];
        flag[0] = (z == 0) ? 1 : 0;
    }
}

__device__ __forceinline__ int edge_src(const int* idx, int e, int E, int is64) {
    return is64 ? idx[2 * e] : idx[e];
}
__device__ __forceinline__ int edge_dst(const int* idx, int e, int E, int is64) {
    return is64 ? idx[2 * (E + e)] : idx[E + e];
}

__global__ void k_count(const int* __restrict__ idx, int* __restrict__ counts,
                        const int* __restrict__ flag, int E) {
    int e = blockIdx.x * blockDim.x + threadIdx.x;
    if (e >= E) return;
    int is64 = flag[0];
    atomicAdd(&counts[edge_dst(idx, e, E, is64)], 1);
}

__global__ void k_dinv(const int* __restrict__ counts, float* __restrict__ dinv, int N) {
    int i = blockIdx.x * blockDim.x + threadIdx.x;
    if (i < N) dinv[i] = rsqrtf((float)(counts[i] + 1));  // +1 self-loop; always > 0
}

// ---- 3-phase exclusive scan of counts[N] -> row_ptr[N+1]
__global__ void k_scan1(const int* __restrict__ counts, int* __restrict__ bsums, int N) {
    __shared__ int s[256];
    int i = blockIdx.x * 256 + threadIdx.x;
    s[threadIdx.x] = (i < N) ? counts[i] : 0;
    __syncthreads();
    for (int st = 128; st > 0; st >>= 1) {
        if (threadIdx.x < st) s[threadIdx.x] += s[threadIdx.x + st];
        __syncthreads();
    }
    if (threadIdx.x == 0) bsums[blockIdx.x] = s[0];
}

__global__ void k_scan2(const int* __restrict__ bsums, int* __restrict__ boffs, int nb) {
    __shared__ int s[512];
    int t = threadIdx.x;
    s[t] = (t < nb) ? bsums[t] : 0;
    __syncthreads();
    for (int st = 1; st < 512; st <<= 1) {
        int v = (t >= st) ? s[t - st] : 0;
        __syncthreads();
        s[t] += v;
        __syncthreads();
    }
    boffs[t] = (t == 0) ? 0 : s[t - 1];  // exclusive
}

__global__ void k_scan3(const int* __restrict__ counts, const int* __restrict__ boffs,
                        int* __restrict__ row_ptr, int N, int E) {
    __shared__ int s[256];
    int i = blockIdx.x * 256 + threadIdx.x;
    int v = (i < N) ? counts[i] : 0;
    s[threadIdx.x] = v;
    __syncthreads();
    for (int st = 1; st < 256; st <<= 1) {
        int u = (threadIdx.x >= st) ? s[threadIdx.x - st] : 0;
        __syncthreads();
        s[threadIdx.x] += u;
        __syncthreads();
    }
    if (i < N) row_ptr[i] = boffs[blockIdx.x] + s[threadIdx.x] - v;  // exclusive
    if (i == 0) row_ptr[N] = E;
}

__global__ void k_fill(const int* __restrict__ idx, const int* __restrict__ row_ptr,
                       int* __restrict__ cursor, int* __restrict__ csr_src,
                       const int* __restrict__ flag, int E) {
    int e = blockIdx.x * blockDim.x + threadIdx.x;
    if (e >= E) return;
    int is64 = flag[0];
    int s_ = edge_src(idx, e, E, is64);
    int d_ = edge_dst(idx, e, E, is64);
    int pos = atomicAdd(&cursor[d_], 1);
    csr_src[row_ptr[d_] + pos] = s_;
}

// ---- layer 1 GEMM: hs1[i,f] = (sum_k x[i,k] * W1[k,f]) * dinv[i], f in [0,64)
// 16 rows/block, 4 rows/thread -> W1 load amortized over 4 FMAs.
__global__ void k_gemm1(const float* __restrict__ x, const float* __restrict__ W1,
                        const float* __restrict__ dinv, float* __restrict__ hs1, int N) {
    __shared__ float xs[16][128];
    int tid = threadIdx.x;
    int rbase = blockIdx.x * 16;
    const float4* xv = (const float4*)x;  // row r at xv[r*32 + c]
    for (int i = tid; i < 512; i += 256) {
        int r = i >> 5, c = i & 31;
        int rr = rbase + r;
        if (rr >= N) rr = N - 1;
        ((float4*)&xs[r][0])[c] = xv[(size_t)rr * 32 + c];
    }
    __syncthreads();
    int f = tid & 63;
    int rs = tid >> 6;  // 0..3
    float a0 = 0.f, a1_ = 0.f, a2 = 0.f, a3 = 0.f;
#pragma unroll 4
    for (int k = 0; k < 128; ++k) {
        float w = W1[k * 64 + f];
        a0 = fmaf(xs[rs][k], w, a0);
        a1_ = fmaf(xs[rs + 4][k], w, a1_);
        a2 = fmaf(xs[rs + 8][k], w, a2);
        a3 = fmaf(xs[rs + 12][k], w, a3);
    }
    int r;
    r = rbase + rs;      if (r < N) hs1[(size_t)r * 64 + f] = a0 * dinv[r];
    r = rbase + rs + 4;  if (r < N) hs1[(size_t)r * 64 + f] = a1_ * dinv[r];
    r = rbase + rs + 8;  if (r < N) hs1[(size_t)r * 64 + f] = a2 * dinv[r];
    r = rbase + rs + 12; if (r < N) hs1[(size_t)r * 64 + f] = a3 * dinv[r];
}

// ---- layer 1 aggregation: one wave per node. Wave = 4 groups x 16 lanes;
// each group gathers a different edge row as float4 (16 lanes x 16B = 256B row).
// Unroll 2 -> 8 independent row loads in flight per wave.
__global__ void k_agg1(const float* __restrict__ hs1, const int* __restrict__ row_ptr,
                       const int* __restrict__ csr_src, const float* __restrict__ dinv,
                       const float* __restrict__ b1, float* __restrict__ a1, int N) {
    int node = (blockIdx.x * blockDim.x + threadIdx.x) >> 6;
    if (node >= N) return;
    int lane = threadIdx.x & 63;
    int g = lane >> 4;    // edge slot 0..3
    int c = lane & 15;    // float4 column
    const float4* H = (const float4*)hs1;  // row i at H[i*16 + c]

    float4 acc = {0.f, 0.f, 0.f, 0.f}, accB = {0.f, 0.f, 0.f, 0.f};
    if (g == 0) acc = H[(size_t)node * 16 + c];  // self-loop (pre-scaled by dinv)

    int beg = row_ptr[node], end = row_ptr[node + 1];
    int e = beg + g;
    for (; e + 4 < end; e += 8) {
        int j0 = csr_src[e];
        int j1 = csr_src[e + 4];
        float4 v0 = H[(size_t)j0 * 16 + c];
        float4 v1 = H[(size_t)j1 * 16 + c];
        add4(acc, v0);
        add4(accB, v1);
    }
    if (e < end) {
        int j = csr_src[e];
        add4(acc, H[(size_t)j * 16 + c]);
    }
    add4(acc, accB);
    // reduce the 4 groups: lanes {c, c+16, c+32, c+48}
    add4(acc, shfl_xor4(acc, 16));
    add4(acc, shfl_xor4(acc, 32));
    if (g == 0) {
        float s = dinv[node];
        float4 bv = ((const float4*)b1)[c];
        float4 o;
        o.x = fmaxf(fmaf(acc.x, s, bv.x), 0.f);
        o.y = fmaxf(fmaf(acc.y, s, bv.y), 0.f);
        o.z = fmaxf(fmaf(acc.z, s, bv.z), 0.f);
        o.w = fmaxf(fmaf(acc.w, s, bv.w), 0.f);
        ((float4*)a1)[(size_t)node * 16 + c] = o;
    }
}

// ---- layer 2 GEMM: hs2[i,f] = (sum_k a1[i,k] * W2[k,f]) * dinv[i], f in [0,32)
// 32 rows/block, 4 rows/thread.
__global__ void k_gemm2(const float* __restrict__ a1, const float* __restrict__ W2,
                        const float* __restrict__ dinv, float* __restrict__ hs2, int N) {
    __shared__ float as[32][64];
    int tid = threadIdx.x;
    int rbase = blockIdx.x * 32;
    const float4* av = (const float4*)a1;  // row r at av[r*16 + c]
    for (int i = tid; i < 512; i += 256) {
        int r = i >> 4, c = i & 15;
        int rr = rbase + r;
        if (rr >= N) rr = N - 1;
        ((float4*)&as[r][0])[c] = av[(size_t)rr * 16 + c];
    }
    __syncthreads();
    int f = tid & 31;
    int rs = tid >> 5;  // 0..7
    float a0 = 0.f, a1_ = 0.f, a2 = 0.f, a3 = 0.f;
#pragma unroll 4
    for (int k = 0; k < 64; ++k) {
        float w = W2[k * 32 + f];
        a0 = fmaf(as[rs][k], w, a0);
        a1_ = fmaf(as[rs + 8][k], w, a1_);
        a2 = fmaf(as[rs + 16][k], w, a2);
        a3 = fmaf(as[rs + 24][k], w, a3);
    }
    int r;
    r = rbase + rs;      if (r < N) hs2[(size_t)r * 32 + f] = a0 * dinv[r];
    r = rbase + rs + 8;  if (r < N) hs2[(size_t)r * 32 + f] = a1_ * dinv[r];
    r = rbase + rs + 16; if (r < N) hs2[(size_t)r * 32 + f] = a2 * dinv[r];
    r = rbase + rs + 24; if (r < N) hs2[(size_t)r * 32 + f] = a3 * dinv[r];
}

// ---- layer 2 aggregation: one wave per node; 8 groups x 8 lanes (32-float rows),
// unroll 2 -> 16 independent row loads in flight.
__global__ void k_agg2(const float* __restrict__ hs2, const int* __restrict__ row_ptr,
                       const int* __restrict__ csr_src, const float* __restrict__ dinv,
                       const float* __restrict__ b2, float* __restrict__ out, int N) {
    int node = (blockIdx.x * blockDim.x + threadIdx.x) >> 6;
    if (node >= N) return;
    int lane = threadIdx.x & 63;
    int g = lane >> 3;   // edge slot 0..7
    int c = lane & 7;    // float4 column
    const float4* H = (const float4*)hs2;  // row i at H[i*8 + c]

    float4 acc = {0.f, 0.f, 0.f, 0.f}, accB = {0.f, 0.f, 0.f, 0.f};
    if (g == 0) acc = H[(size_t)node * 8 + c];  // self-loop

    int beg = row_ptr[node], end = row_ptr[node + 1];
    int e = beg + g;
    for (; e + 8 < end; e += 16) {
        int j0 = csr_src[e];
        int j1 = csr_src[e + 8];
        float4 v0 = H[(size_t)j0 * 8 + c];
        float4 v1 = H[(size_t)j1 * 8 + c];
        add4(acc, v0);
        add4(accB, v1);
    }
    if (e < end) {
        int j = csr_src[e];
        add4(acc, H[(size_t)j * 8 + c]);
    }
    add4(acc, accB);
    // reduce the 8 groups: xor 8, 16, 32
    add4(acc, shfl_xor4(acc, 8));
    add4(acc, shfl_xor4(acc, 16));
    add4(acc, shfl_xor4(acc, 32));
    if (g == 0) {
        float s = dinv[node];
        float4 bv = ((const float4*)b2)[c];
        float4 o;
        o.x = fmaf(acc.x, s, bv.x);
        o.y = fmaf(acc.y, s, bv.y);
        o.z = fmaf(acc.z, s, bv.z);
        o.w = fmaf(acc.w, s, bv.w);
        ((float4*)out)[(size_t)node * 8 + c] = o;
    }
}

extern "C" void kernel_launch(void* const* d_in, const int* in_sizes, int n_in,
                              void* d_out, int out_size, void* d_ws, size_t ws_size,
                              hipStream_t stream) {
    const float* x  = (const float*)d_in[0];
    const int*   idx = (const int*)d_in[1];
    const float* W1 = (const float*)d_in[2];
    const float* b1 = (const float*)d_in[3];
    const float* W2 = (const float*)d_in[4];
    const float* b2 = (const float*)d_in[5];
    float* out = (float*)d_out;

    const int N = in_sizes[0] / 128;   // 100000
    const int E = in_sizes[1] / 2;     // 1600000

    // workspace layout (256B aligned)
    char* ws = (char*)d_ws;
    size_t off = 0;
    auto alloc = [&](size_t bytes) -> char* {
        char* p = ws + off;
        off = (off + bytes + 255) & ~(size_t)255;
        return p;
    };
    int*   flag    = (int*)alloc(4);
    float* dinv    = (float*)alloc((size_t)N * 4);
    int*   counts  = (int*)alloc((size_t)N * 4);
    int*   row_ptr = (int*)alloc((size_t)(N + 1) * 4);
    int*   bsums   = (int*)alloc(512 * 4);
    int*   boffs   = (int*)alloc(512 * 4);
    int*   csr_src = (int*)alloc((size_t)E * 4);
    float* hs1     = (float*)alloc((size_t)N * 64 * 4);
    float* a1      = (float*)alloc((size_t)N * 64 * 4);
    float* hs2     = hs1;  // reuse: hs1 dead after k_agg1

    const int nb  = (N + 255) / 256;           // scan blocks (391 <= 512)
    const int ebk = (E + BLK - 1) / BLK;

    hipMemsetAsync(counts, 0, (size_t)N * 4, stream);
    k_detect<<<1, 1, 0, stream>>>(idx, flag);
    k_count<<<ebk, BLK, 0, stream>>>(idx, counts, flag, E);
    k_dinv<<<(N + BLK - 1) / BLK, BLK, 0, stream>>>(counts, dinv, N);
    k_scan1<<<nb, 256, 0, stream>>>(counts, bsums, N);
    k_scan2<<<1, 512, 0, stream>>>(bsums, boffs, nb);
    k_scan3<<<nb, 256, 0, stream>>>(counts, boffs, row_ptr, N, E);
    hipMemsetAsync(counts, 0, (size_t)N * 4, stream);  // reuse as fill cursor
    k_fill<<<ebk, BLK, 0, stream>>>(idx, row_ptr, counts, csr_src, flag, E);

    k_gemm1<<<(N + 15) / 16, 256, 0, stream>>>(x, W1, dinv, hs1, N);
    k_agg1<<<(N + 3) / 4, 256, 0, stream>>>(hs1, row_ptr, csr_src, dinv, b1, a1, N);
    k_gemm2<<<(N + 31) / 32, 256, 0, stream>>>(a1, W2, dinv, hs2, N);
    k_agg2<<<(N + 3) / 4, 256, 0, stream>>>(hs2, row_ptr, csr_src, dinv, b2, out, N);
}